// Round 4
// baseline (788.778 us; speedup 1.0000x reference)
//
#include <hip/hip_runtime.h>
#include <stdint.h>
#include <math.h>

#define BATCH 32768
#define LDIM 128
#define HID 20

// workspace layout (floats): repacked wave-contiguous weights
#define WS_WHH 0        // [wv][kl][ty][j]   4*5*4*20 = 1600
#define WS_WI2 1600     // [wv][kl][s][j8]   4*5*2*8  = 320
#define WS_WC  1920     // [wv][col][i20]    4*127*20 = 10160
#define WS_TOTAL 12080

// =====================================================================
// eps: jax.random.normal(key(42), (128,32768), f32), partitionable
// threefry (counters (0,n), output o0^o1) — VERIFIED PASSING (r4/r5,
// absmax 0.0156 = 1 bf16 ulp). Do not touch.
// =====================================================================

__device__ __forceinline__ void threefry2x32(uint32_t x0, uint32_t x1,
                                             uint32_t& o0, uint32_t& o1) {
  const uint32_t k0 = 0u, k1 = 42u;
  const uint32_t k2 = k0 ^ k1 ^ 0x1BD11BDAu;
  uint32_t v0 = x0 + k0, v1 = x1 + k1;
#define TF_R(r) { v0 += v1; v1 = (v1 << (r)) | (v1 >> (32 - (r))); v1 ^= v0; }
  TF_R(13) TF_R(15) TF_R(26) TF_R(6)
  v0 += k1; v1 += k2 + 1u;
  TF_R(17) TF_R(29) TF_R(16) TF_R(24)
  v0 += k2; v1 += k0 + 2u;
  TF_R(13) TF_R(15) TF_R(26) TF_R(6)
  v0 += k0; v1 += k1 + 3u;
  TF_R(17) TF_R(29) TF_R(16) TF_R(24)
  v0 += k1; v1 += k2 + 4u;
  TF_R(13) TF_R(15) TF_R(26) TF_R(6)
  v0 += k2; v1 += k0 + 5u;
#undef TF_R
  o0 = v0; o1 = v1;
}

__device__ __forceinline__ float erfinv_xla_f32(float x) {
  float t = __fmul_rn(x, x);
  float w = -(float)log1p(-(double)t);   // correctly-rounded f32 log1p
  float p;
  if (w < 5.0f) {
    w = __fadd_rn(w, -2.5f);
    p = 2.81022636e-08f;
    p = __fadd_rn(__fmul_rn(p, w), 3.43273939e-07f);
    p = __fadd_rn(__fmul_rn(p, w), -3.5233877e-06f);
    p = __fadd_rn(__fmul_rn(p, w), -4.39150654e-06f);
    p = __fadd_rn(__fmul_rn(p, w), 0.00021858087f);
    p = __fadd_rn(__fmul_rn(p, w), -0.00125372503f);
    p = __fadd_rn(__fmul_rn(p, w), -0.00417768164f);
    p = __fadd_rn(__fmul_rn(p, w), 0.246640727f);
    p = __fadd_rn(__fmul_rn(p, w), 1.50140941f);
  } else {
    w = __fadd_rn(__fsqrt_rn(w), -3.0f);
    p = -0.000200214257f;
    p = __fadd_rn(__fmul_rn(p, w), 0.000100950558f);
    p = __fadd_rn(__fmul_rn(p, w), 0.00134934322f);
    p = __fadd_rn(__fmul_rn(p, w), -0.00367342844f);
    p = __fadd_rn(__fmul_rn(p, w), 0.00573950773f);
    p = __fadd_rn(__fmul_rn(p, w), -0.0076224613f);
    p = __fadd_rn(__fmul_rn(p, w), 0.00943887047f);
    p = __fadd_rn(__fmul_rn(p, w), 1.00167406f);
    p = __fadd_rn(__fmul_rn(p, w), 2.83297682f);
  }
  return __fmul_rn(p, x);
}

__device__ __forceinline__ float eps_val(int t, int b) {
  uint32_t n = (uint32_t)t * 32768u + (uint32_t)b;
  uint32_t o0, o1;
  threefry2x32(0u, n, o0, o1);
  uint32_t bits = o0 ^ o1;
  const float lo    = __uint_as_float(0xBF7FFFFFu);
  const float sqrt2 = __uint_as_float(0x3FB504F3u);
  float f = __fadd_rn(__uint_as_float((bits >> 9) | 0x3F800000u), -1.0f);
  float u = __fadd_rn(__fmul_rn(f, 2.0f), lo);
  u = fmaxf(u, lo);
  return __fmul_rn(sqrt2, erfinv_xla_f32(u));
}

__device__ __forceinline__ float fexp2(float x) { return __builtin_amdgcn_exp2f(x); }
__device__ __forceinline__ float frcp(float x)  { return __builtin_amdgcn_rcpf(x); }
__device__ __forceinline__ float fexp(float x)  { return fexp2(1.442695040888963f * x); }
__device__ __forceinline__ float sigm(float x)  { return frcp(1.0f + fexp2(-1.442695040888963f * x)); }
__device__ __forceinline__ float tanhx(float x) { return 1.0f - 2.0f * frcp(1.0f + fexp2(2.885390081777926f * x)); }

// pure copy/permute — values bit-identical, just wave-contiguous layouts so
// the main kernel's per-step scalar fetches are a few s_load_dwordx16 instead
// of ~160 scattered s_load_dword (r3's dominant latency).
__global__ void repack_kernel(const float* __restrict__ W_ih1,
                              const float* __restrict__ W_hh1,
                              const float* __restrict__ W_ih2,
                              float* __restrict__ ws) {
  const int stride = gridDim.x * blockDim.x;
  const int tid0 = blockIdx.x * blockDim.x + threadIdx.x;
  for (int idx = tid0; idx < 1600; idx += stride) {       // Whh1 [wv][kl][ty][j]
    int j = idx % 20, r = idx / 20;     // r = (wv*5+kl)*4+ty
    int ty = r & 3, rk = r >> 2;        // rk = wv*5+kl = k index
    ws[WS_WHH + idx] = W_hh1[(ty * 20 + rk) * 20 + j];
  }
  for (int idx = tid0; idx < 320; idx += stride) {        // Wih2 [wv][kl][s][j]
    int j = idx & 7, r = idx >> 3;      // r = (wv*5+kl)*2+s
    int s = r & 1, rk = r >> 1;
    ws[WS_WI2 + idx] = W_ih2[j * 40 + s * 20 + rk];
  }
  for (int idx = tid0; idx < 10160; idx += stride) {      // Wih1T [wv][col][i]
    int i = idx % 20, rc = idx / 20;
    int col = rc % 127, wv = rc / 127;
    int ty = i / 5, kl = i % 5;
    int g = ty * 20 + wv * 5 + kl;
    ws[WS_WC + idx] = W_ih1[g * 127 + col];
  }
}

// V5: role-per-wave (r3) + repacked contiguous scalar weights + LSTM2
// replicated on all 4 waves (no h2 exchange, no wave-0/1 tail serialization,
// same-step stores). All FP op orderings identical to r3 → bit-identical out.
__global__ __launch_bounds__(256, 2) void sampler_kernel(
    const float* __restrict__ mu, const float* __restrict__ log_var,
    const float* __restrict__ ws,
    const float* __restrict__ b_ih1, const float* __restrict__ b_hh1,
    const float* __restrict__ W_hh2,
    const float* __restrict__ b_ih2, const float* __restrict__ b_hh2,
    float* __restrict__ out) {
  // exchange buffers, lane-stride-4B (conflict-free), double-buffered
  __shared__ float hbuf[2][HID][64];     // [buf][k][elem]   h1 state
  __shared__ float gbuf[2][8][4][64];    // [buf][j][wave][elem] g2 partials
  __shared__ float epsbuf[2][4][64];     // [group&1][slot][elem] eps ring

  const int tid  = threadIdx.x;
  const int lane = tid & 63;
  const int wv   = __builtin_amdgcn_readfirstlane(tid >> 6);  // uniform
  const int wv5  = wv * 5;
  const int elem = blockIdx.x * 64 + lane;
  const float* mrow = mu + (size_t)elem * LDIM;

  // wave-local weight bases (uniform → scalar loads)
  const float* Whh  = ws + WS_WHH + wv5 * 80;          // + kl*80 : 4 rows × 20
  const float* Wi2  = ws + WS_WI2 + wv5 * 16;          // + kl*16 : lh[8], lc[8]
  const float* Wcol = ws + WS_WC  + wv * (127 * 20);   // + col*20

  // first_input (replicated on all 4 waves; bit-identical)
  float eps0 = eps_val(0, elem);
  float m0 = mrow[0];
  float fi = fmaf(eps0, fexp(0.5f * log_var[(size_t)elem * LDIM]), m0);

  // acc[i], i = ty*5+kl — this wave's 20 gate accumulators, bias folded.
  float acc[20];
#pragma unroll
  for (int i = 0; i < 20; ++i) {
    const int ty = i / 5, kl = i % 5;
    const int g = ty * 20 + wv5 + kl;                  // uniform
    acc[i] = fmaf(fi, Wcol[i], b_ih1[g] + b_hh1[g]);   // Wcol col 0
  }

  float h[HID];
#pragma unroll
  for (int j = 0; j < HID; ++j) h[j] = 0.0f;
  float cst[5];
#pragma unroll
  for (int k = 0; k < 5; ++k) cst[k] = 0.0f;
  float h2a = 0.0f, h2b = 0.0f, c2a = 0.0f, c2b = 0.0f;  // replicated

  float* out_mu = out;
  float* out_lv = out + (size_t)BATCH * LDIM;
  float* out_sp = out + 2 * (size_t)BATCH * LDIM;
  const size_t rowoff = (size_t)elem * LDIM;
  if (wv == 2)      out_sp[rowoff] = fi;
  else if (wv == 3) { out_mu[rowoff] = 0.0f; out_lv[rowoff] = 1.0f; }

  float xm_pref = m0;

  for (int t = 1; t < LDIM; ++t) {
    const int buf = t & 1;
    float xm = xm_pref;
    xm_pref = mrow[t];

    // ---- eps ring: at group start, wave w computes eps(t+w) covering
    // consumers t..t+3 (slot p = eps(t0+p), consumer reads slot (t-1)&3) ----
    if (((t - 1) & 3) == 0)
      epsbuf[((t - 1) >> 2) & 1][wv][lane] = eps_val(t + wv, elem);

    // ---- maintain acc = bias + (input cols) @ W_ih1^T (prefix trick) ----
    if (t >= 2) {
      if (t == 2) {
        float d0 = m0 - fi;   // col 0 switches first_input -> mu[:,0]
#pragma unroll
        for (int i = 0; i < 20; ++i) acc[i] = fmaf(d0, Wcol[i], acc[i]);
      }
      const float* wc = Wcol + (t - 1) * 20;           // contiguous 20 dwords
#pragma unroll
      for (int i = 0; i < 20; ++i) acc[i] = fmaf(xm, wc[i], acc[i]);
    }

    // ---- LSTM1 gates (contiguous scalar weights), cell, LSTM2 partials ----
    float g2p[8];
#pragma unroll
    for (int j = 0; j < 8; ++j) g2p[j] = 0.0f;

#pragma unroll
    for (int kl = 0; kl < 5; ++kl) {
      float s0 = acc[kl], s1 = acc[5 + kl], s2 = acc[10 + kl], s3 = acc[15 + kl];
      const float* w0 = Whh + kl * 80;                 // 80 contiguous dwords
      const float* w1 = w0 + 20;
      const float* w2r = w0 + 40;
      const float* w3 = w0 + 60;
#pragma unroll
      for (int j = 0; j < HID; ++j) {
        const float hj = h[j];
        s0 = fmaf(hj, w0[j], s0);
        s1 = fmaf(hj, w1[j], s1);
        s2 = fmaf(hj, w2r[j], s2);
        s3 = fmaf(hj, w3[j], s3);
      }
      float ik = sigm(s0), fk = sigm(s1), gk = tanhx(s2), ok = sigm(s3);
      float cn = fmaf(fk, cst[kl], ik * gk);
      cst[kl] = cn;
      float hk = ok * tanhx(cn);
      hbuf[buf][wv5 + kl][lane] = hk;                  // stride-4B, free
      float lh = (hk >= 0.0f) ? hk : 0.01f * hk;
      float lc = (cn >= 0.0f) ? cn : 0.01f * cn;
      const float* u = Wi2 + kl * 16;                  // 16 contiguous dwords
#pragma unroll
      for (int j = 0; j < 8; ++j) g2p[j] = fmaf(lh, u[j], g2p[j]);
#pragma unroll
      for (int j = 0; j < 8; ++j) g2p[j] = fmaf(lc, u[8 + j], g2p[j]);
    }

#pragma unroll
    for (int j = 0; j < 8; ++j) gbuf[buf][j][wv][lane] = g2p[j];

    __syncthreads();   // one barrier per step; all exchanges double-buffered

    // ---- next-step h (all waves) ----
#pragma unroll
    for (int j = 0; j < HID; ++j) h[j] = hbuf[buf][j][lane];

    // ---- LSTM2: reduce partials + cell, REPLICATED on all 4 waves ----
    float g2[8];
#pragma unroll
    for (int j = 0; j < 8; ++j) {
      float p0 = gbuf[buf][j][0][lane];
      float p1 = gbuf[buf][j][1][lane];
      float p2 = gbuf[buf][j][2][lane];
      float p3 = gbuf[buf][j][3][lane];
      float v = (p0 + p1) + (p2 + p3);                 // matches r3 order
      g2[j] = fmaf(h2a, W_hh2[2 * j],
                   fmaf(h2b, W_hh2[2 * j + 1], b_ih2[j] + b_hh2[j])) + v;
    }
    float i20 = sigm(g2[0]), i21 = sigm(g2[1]);
    float f20 = sigm(g2[2]), f21 = sigm(g2[3]);
    float t20 = tanhx(g2[4]), t21 = tanhx(g2[5]);
    float o20 = sigm(g2[6]), o21 = sigm(g2[7]);
    c2a = fmaf(f20, c2a, i20 * t20);
    c2b = fmaf(f21, c2b, i21 * t21);
    h2a = o20 * tanhx(c2a);
    h2b = o21 * tanhx(c2b);

    // ---- same-step stores (role-split by wave) ----
    if (wv == 2) {
      float eps_t = epsbuf[((t - 1) >> 2) & 1][(t - 1) & 3][lane];
      out_sp[rowoff + t] = fmaf(eps_t, fexp(0.5f * h2b), h2a);
    } else if (wv == 3) {
      out_mu[rowoff + t] = h2a;
      out_lv[rowoff + t] = h2b;
    }
  }
}

extern "C" void kernel_launch(void* const* d_in, const int* in_sizes, int n_in,
                              void* d_out, int out_size, void* d_ws, size_t ws_size,
                              hipStream_t stream) {
  (void)in_sizes; (void)n_in; (void)ws_size; (void)out_size;
  const float* mu      = (const float*)d_in[0];
  const float* log_var = (const float*)d_in[1];
  const float* W_ih1   = (const float*)d_in[2];
  const float* W_hh1   = (const float*)d_in[3];
  const float* b_ih1   = (const float*)d_in[4];
  const float* b_hh1   = (const float*)d_in[5];
  const float* W_ih2   = (const float*)d_in[6];
  const float* W_hh2   = (const float*)d_in[7];
  const float* b_ih2   = (const float*)d_in[8];
  const float* b_hh2   = (const float*)d_in[9];
  float* out = (float*)d_out;
  float* ws  = (float*)d_ws;   // needs 12080 floats = 48.3 KB

  repack_kernel<<<dim3(8), dim3(256), 0, stream>>>(W_ih1, W_hh1, W_ih2, ws);
  dim3 grid(BATCH / 64), block(256);   // 1 elem/lane, 4 role-waves, 2 blk/CU
  sampler_kernel<<<grid, block, 0, stream>>>(mu, log_var, ws, b_ih1, b_hh1,
                                             W_hh2, b_ih2, b_hh2, out);
}

// Round 5
// 779.172 us; speedup vs baseline: 1.0123x; 1.0123x over previous
//
#include <hip/hip_runtime.h>
#include <stdint.h>
#include <math.h>

#define BATCH 32768
#define LDIM 128
#define HID 20

// workspace layout (floats): repacked wave-contiguous weights (8-wave split)
#define WS_WHH 0        // [wv8][kl][tyl][j20]  8*5*2*20 = 1600
#define WS_WI2 1600     // [kr][kl][s][j8]      4*5*2*8  = 320
#define WS_WC  1920     // [wv8][col][i10]      8*127*10 = 10160
#define WS_TOTAL 12080

// =====================================================================
// eps: jax.random.normal(key(42), (128,32768), f32), partitionable
// threefry (counters (0,n), output o0^o1) — VERIFIED PASSING (r4/r5,
// absmax 0.0156 = 1 bf16 ulp). Do not touch.
// =====================================================================

__device__ __forceinline__ void threefry2x32(uint32_t x0, uint32_t x1,
                                             uint32_t& o0, uint32_t& o1) {
  const uint32_t k0 = 0u, k1 = 42u;
  const uint32_t k2 = k0 ^ k1 ^ 0x1BD11BDAu;
  uint32_t v0 = x0 + k0, v1 = x1 + k1;
#define TF_R(r) { v0 += v1; v1 = (v1 << (r)) | (v1 >> (32 - (r))); v1 ^= v0; }
  TF_R(13) TF_R(15) TF_R(26) TF_R(6)
  v0 += k1; v1 += k2 + 1u;
  TF_R(17) TF_R(29) TF_R(16) TF_R(24)
  v0 += k2; v1 += k0 + 2u;
  TF_R(13) TF_R(15) TF_R(26) TF_R(6)
  v0 += k0; v1 += k1 + 3u;
  TF_R(17) TF_R(29) TF_R(16) TF_R(24)
  v0 += k1; v1 += k2 + 4u;
  TF_R(13) TF_R(15) TF_R(26) TF_R(6)
  v0 += k2; v1 += k0 + 5u;
#undef TF_R
  o0 = v0; o1 = v1;
}

__device__ __forceinline__ float erfinv_xla_f32(float x) {
  float t = __fmul_rn(x, x);
  float w = -(float)log1p(-(double)t);   // correctly-rounded f32 log1p
  float p;
  if (w < 5.0f) {
    w = __fadd_rn(w, -2.5f);
    p = 2.81022636e-08f;
    p = __fadd_rn(__fmul_rn(p, w), 3.43273939e-07f);
    p = __fadd_rn(__fmul_rn(p, w), -3.5233877e-06f);
    p = __fadd_rn(__fmul_rn(p, w), -4.39150654e-06f);
    p = __fadd_rn(__fmul_rn(p, w), 0.00021858087f);
    p = __fadd_rn(__fmul_rn(p, w), -0.00125372503f);
    p = __fadd_rn(__fmul_rn(p, w), -0.00417768164f);
    p = __fadd_rn(__fmul_rn(p, w), 0.246640727f);
    p = __fadd_rn(__fmul_rn(p, w), 1.50140941f);
  } else {
    w = __fadd_rn(__fsqrt_rn(w), -3.0f);
    p = -0.000200214257f;
    p = __fadd_rn(__fmul_rn(p, w), 0.000100950558f);
    p = __fadd_rn(__fmul_rn(p, w), 0.00134934322f);
    p = __fadd_rn(__fmul_rn(p, w), -0.00367342844f);
    p = __fadd_rn(__fmul_rn(p, w), 0.00573950773f);
    p = __fadd_rn(__fmul_rn(p, w), -0.0076224613f);
    p = __fadd_rn(__fmul_rn(p, w), 0.00943887047f);
    p = __fadd_rn(__fmul_rn(p, w), 1.00167406f);
    p = __fadd_rn(__fmul_rn(p, w), 2.83297682f);
  }
  return __fmul_rn(p, x);
}

__device__ __forceinline__ float eps_val(int t, int b) {
  uint32_t n = (uint32_t)t * 32768u + (uint32_t)b;
  uint32_t o0, o1;
  threefry2x32(0u, n, o0, o1);
  uint32_t bits = o0 ^ o1;
  const float lo    = __uint_as_float(0xBF7FFFFFu);
  const float sqrt2 = __uint_as_float(0x3FB504F3u);
  float f = __fadd_rn(__uint_as_float((bits >> 9) | 0x3F800000u), -1.0f);
  float u = __fadd_rn(__fmul_rn(f, 2.0f), lo);
  u = fmaxf(u, lo);
  return __fmul_rn(sqrt2, erfinv_xla_f32(u));
}

__device__ __forceinline__ float fexp2(float x) { return __builtin_amdgcn_exp2f(x); }
__device__ __forceinline__ float frcp(float x)  { return __builtin_amdgcn_rcpf(x); }
__device__ __forceinline__ float fexp(float x)  { return fexp2(1.442695040888963f * x); }
__device__ __forceinline__ float sigm(float x)  { return frcp(1.0f + fexp2(-1.442695040888963f * x)); }
__device__ __forceinline__ float tanhx(float x) { return 1.0f - 2.0f * frcp(1.0f + fexp2(2.885390081777926f * x)); }

// pure copy/permute — values bit-identical, wave-contiguous layouts for the
// 8-wave (tp,kr) split: wave wv = tp*4+kr owns types {2tp,2tp+1} of
// k = kr*5+kl.
__global__ void repack_kernel(const float* __restrict__ W_ih1,
                              const float* __restrict__ W_hh1,
                              const float* __restrict__ W_ih2,
                              float* __restrict__ ws) {
  const int stride = gridDim.x * blockDim.x;
  const int tid0 = blockIdx.x * blockDim.x + threadIdx.x;
  for (int idx = tid0; idx < 1600; idx += stride) {   // Whh [wv][kl][tyl][j]
    int j = idx % 20, r = idx / 20;     // r = (wv*5+kl)*2+tyl
    int tyl = r & 1, rkl = r >> 1;
    int kl = rkl % 5, wv = rkl / 5;
    int tp = wv >> 2, kr = wv & 3;
    int g = (2 * tp + tyl) * 20 + kr * 5 + kl;
    ws[WS_WHH + idx] = W_hh1[g * 20 + j];
  }
  for (int idx = tid0; idx < 320; idx += stride) {    // Wi2 [kr][kl][s][j]
    int j = idx & 7, r = idx >> 3;      // r = (kr*5+kl)*2+s
    int s = r & 1, rk = r >> 1;         // rk = k index 0..19
    ws[WS_WI2 + idx] = W_ih2[j * 40 + s * 20 + rk];
  }
  for (int idx = tid0; idx < 10160; idx += stride) {  // Wc [wv][col][i10]
    int i = idx % 10, rc = idx / 10;
    int col = rc % 127, wv = rc / 127;
    int tp = wv >> 2, kr = wv & 3;
    int tyl = i / 5, kl = i % 5;
    int g = (2 * tp + tyl) * 20 + kr * 5 + kl;
    ws[WS_WC + idx] = W_ih1[g * 127 + col];
  }
}

// V6: 8-wave split for 2x wave count (4 waves/SIMD vs r4's 2).
// Wave (tp,kr): tp=0 computes gate types {i,f}, tp=1 computes {g,o}, for
// k in [5*kr, 5*kr+5), full 20-j dot (200 fma) — weights stay wave-uniform
// (scalar s_load). Cell coupling i,f <-> g,o via one LDS exchange (gko) +
// barrier; h exchange as before (2 barriers/step total). LSTM2 on wave
// (1,0) only, h2 double-buffered, stores lag one step (as r3). All FP op
// orderings identical to r4 -> values unchanged.
__global__ __launch_bounds__(512, 4) void sampler_kernel(
    const float* __restrict__ mu, const float* __restrict__ log_var,
    const float* __restrict__ ws,
    const float* __restrict__ b_ih1, const float* __restrict__ b_hh1,
    const float* __restrict__ W_hh2,
    const float* __restrict__ b_ih2, const float* __restrict__ b_hh2,
    float* __restrict__ out) {
  // all lane-stride-4B (conflict-free). Single-buffered where the 2-barrier
  // schedule already separates producer/consumer epochs (see phase notes).
  __shared__ float hbuf[HID][64];        // h1(t): written B, read C
  __shared__ float gko[4][5][2][64];     // gk,ok: written A, read B
  __shared__ float gbuf[8][4][64];       // g2 partials: written B, read C
  __shared__ float h2buf[2][2][64];      // h2 (dbuf: crosses steps)
  __shared__ float epsbuf[2][4][64];     // eps ring (8-step period)

  const int tid  = threadIdx.x;
  const int lane = tid & 63;
  const int wv   = __builtin_amdgcn_readfirstlane(tid >> 6);  // 0..7 uniform
  const int tp   = wv >> 2;             // 0: types i,f   1: types g,o
  const int kr   = wv & 3;              // k = kr*5 + kl
  const int elem = blockIdx.x * 64 + lane;
  const float* mrow = mu + (size_t)elem * LDIM;

  // wave-local weight bases (uniform → scalar loads)
  const float* Whh  = ws + WS_WHH + wv * 200;          // + kl*40: 2 rows × 20
  const float* Wi2  = ws + WS_WI2 + kr * 80;           // tp0: + kl*16
  const float* Wcol = ws + WS_WC  + wv * (127 * 10);   // + col*10

  // first_input (replicated on all 8 waves; bit-identical)
  float eps0 = eps_val(0, elem);
  float m0 = mrow[0];
  float fi = fmaf(eps0, fexp(0.5f * log_var[(size_t)elem * LDIM]), m0);

  // acc[i], i = tyl*5+kl — this wave's 10 gate accumulators, bias folded.
  float acc[10];
#pragma unroll
  for (int i = 0; i < 10; ++i) {
    const int tyl = i / 5, kl = i % 5;
    const int g = (2 * tp + tyl) * 20 + kr * 5 + kl;   // uniform
    acc[i] = fmaf(fi, Wcol[i], b_ih1[g] + b_hh1[g]);   // Wcol col 0
  }

  float h[HID];
#pragma unroll
  for (int j = 0; j < HID; ++j) h[j] = 0.0f;
  float cst[5];                                        // live on tp==0 waves
#pragma unroll
  for (int k = 0; k < 5; ++k) cst[k] = 0.0f;
  float h2a = 0.0f, h2b = 0.0f, c2a = 0.0f, c2b = 0.0f;  // live on wave (1,0)

  float* out_mu = out;
  float* out_lv = out + (size_t)BATCH * LDIM;
  float* out_sp = out + 2 * (size_t)BATCH * LDIM;
  const size_t rowoff = (size_t)elem * LDIM;
  if (wv == 5)      out_sp[rowoff] = fi;
  else if (wv == 6) { out_mu[rowoff] = 0.0f; out_lv[rowoff] = 1.0f; }

  float xm_pref = m0;

  for (int t = 1; t < LDIM; ++t) {
    const int buf = t & 1;
    float xm = xm_pref;
    xm_pref = mrow[t];

    // ======== phase A (all waves) ========
    // eps ring: tp1 waves produce eps((t-1)+kr) every 4 steps (slot kr)
    if (tp == 1 && ((t - 1) & 3) == 0)
      epsbuf[((t - 1) >> 2) & 1][kr][lane] = eps_val((t - 1) + kr, elem);

    // maintain acc = bias + (input cols) @ W_ih1^T (prefix trick)
    if (t >= 2) {
      if (t == 2) {
        float d0 = m0 - fi;   // col 0 switches first_input -> mu[:,0]
#pragma unroll
        for (int i = 0; i < 10; ++i) acc[i] = fmaf(d0, Wcol[i], acc[i]);
      }
      const float* wc = Wcol + (t - 1) * 10;           // contiguous 10 dwords
#pragma unroll
      for (int i = 0; i < 10; ++i) acc[i] = fmaf(xm, wc[i], acc[i]);
    }

    // this wave's 10 dots (2 types × 5 k), per-gate FP order == r4
    float a0[5], a1[5];     // tp0: ik,fk    tp1: gk,ok
#pragma unroll
    for (int kl = 0; kl < 5; ++kl) {
      float s0 = acc[kl], s1 = acc[5 + kl];
      const float* w0 = Whh + kl * 40;                 // 40 contiguous dwords
      const float* w1 = w0 + 20;
#pragma unroll
      for (int j = 0; j < HID; ++j) {
        const float hj = h[j];
        s0 = fmaf(hj, w0[j], s0);
        s1 = fmaf(hj, w1[j], s1);
      }
      if (tp == 0) { a0[kl] = sigm(s0);  a1[kl] = sigm(s1); }   // ik, fk
      else         { a0[kl] = tanhx(s0); a1[kl] = sigm(s1); }   // gk, ok
    }
    if (tp == 1) {
#pragma unroll
      for (int kl = 0; kl < 5; ++kl) {
        gko[kr][kl][0][lane] = a0[kl];                 // gk
        gko[kr][kl][1][lane] = a1[kl];                 // ok
      }
    }

    __syncthreads();   // barrier 1: gko ready

    // ======== phase B (tp0 waves): cell + fused LSTM2 partials ========
    if (tp == 0) {
      float g2p[8];
#pragma unroll
      for (int j = 0; j < 8; ++j) g2p[j] = 0.0f;
#pragma unroll
      for (int kl = 0; kl < 5; ++kl) {
        float gk = gko[kr][kl][0][lane];
        float ok = gko[kr][kl][1][lane];
        float cn = fmaf(a1[kl], cst[kl], a0[kl] * gk); // fk*c + ik*gk
        cst[kl] = cn;
        float hk = ok * tanhx(cn);
        hbuf[kr * 5 + kl][lane] = hk;
        float lh = (hk >= 0.0f) ? hk : 0.01f * hk;
        float lc = (cn >= 0.0f) ? cn : 0.01f * cn;
        const float* u = Wi2 + kl * 16;                // 16 contiguous dwords
#pragma unroll
        for (int j = 0; j < 8; ++j) g2p[j] = fmaf(lh, u[j], g2p[j]);
#pragma unroll
        for (int j = 0; j < 8; ++j) g2p[j] = fmaf(lc, u[8 + j], g2p[j]);
      }
#pragma unroll
      for (int j = 0; j < 8; ++j) gbuf[j][kr][lane] = g2p[j];
    }

    __syncthreads();   // barrier 2: hbuf + gbuf ready

    // ======== phase C ========
#pragma unroll
    for (int j = 0; j < HID; ++j) h[j] = hbuf[j][lane];

    if (wv == 4) {
      // wave (1,0): LSTM2 reduce + cell (sole owner of h2/c2 state)
      float g2[8];
#pragma unroll
      for (int j = 0; j < 8; ++j) {
        float p0 = gbuf[j][0][lane];
        float p1 = gbuf[j][1][lane];
        float p2 = gbuf[j][2][lane];
        float p3 = gbuf[j][3][lane];
        float v = (p0 + p1) + (p2 + p3);               // matches r4 order
        g2[j] = fmaf(h2a, W_hh2[2 * j],
                     fmaf(h2b, W_hh2[2 * j + 1], b_ih2[j] + b_hh2[j])) + v;
      }
      float i20 = sigm(g2[0]), i21 = sigm(g2[1]);
      float f20 = sigm(g2[2]), f21 = sigm(g2[3]);
      float t20 = tanhx(g2[4]), t21 = tanhx(g2[5]);
      float o20 = sigm(g2[6]), o21 = sigm(g2[7]);
      c2a = fmaf(f20, c2a, i20 * t20);
      c2b = fmaf(f21, c2b, i21 * t21);
      h2a = o20 * tanhx(c2a);
      h2b = o21 * tanhx(c2b);
      h2buf[buf][0][lane] = h2a;
      h2buf[buf][1][lane] = h2b;
    } else if (wv == 5) {
      if (t >= 2) {                                    // sample for col t-1
        const int e = t - 1;
        float h2a_p = h2buf[buf ^ 1][0][lane];
        float h2b_p = h2buf[buf ^ 1][1][lane];
        float eps_t = epsbuf[(e >> 2) & 1][e & 3][lane];
        out_sp[rowoff + e] = fmaf(eps_t, fexp(0.5f * h2b_p), h2a_p);
      }
    } else if (wv == 6) {
      if (t >= 2) {                                    // mu/lv for col t-1
        out_mu[rowoff + (t - 1)] = h2buf[buf ^ 1][0][lane];
        out_lv[rowoff + (t - 1)] = h2buf[buf ^ 1][1][lane];
      }
    }
  }

  // ---- drain col 127 (t=127 wrote h2buf[1]) ----
  __syncthreads();
  if (wv == 5) {
    float eps_t = epsbuf[1][3][lane];                  // eps(127): grp 31
    out_sp[rowoff + 127] = fmaf(eps_t, fexp(0.5f * h2buf[1][1][lane]),
                                h2buf[1][0][lane]);
  } else if (wv == 6) {
    out_mu[rowoff + 127] = h2buf[1][0][lane];
    out_lv[rowoff + 127] = h2buf[1][1][lane];
  }
}

extern "C" void kernel_launch(void* const* d_in, const int* in_sizes, int n_in,
                              void* d_out, int out_size, void* d_ws, size_t ws_size,
                              hipStream_t stream) {
  (void)in_sizes; (void)n_in; (void)ws_size; (void)out_size;
  const float* mu      = (const float*)d_in[0];
  const float* log_var = (const float*)d_in[1];
  const float* W_ih1   = (const float*)d_in[2];
  const float* W_hh1   = (const float*)d_in[3];
  const float* b_ih1   = (const float*)d_in[4];
  const float* b_hh1   = (const float*)d_in[5];
  const float* W_ih2   = (const float*)d_in[6];
  const float* W_hh2   = (const float*)d_in[7];
  const float* b_ih2   = (const float*)d_in[8];
  const float* b_hh2   = (const float*)d_in[9];
  float* out = (float*)d_out;
  float* ws  = (float*)d_ws;   // needs 12080 floats = 48.3 KB

  repack_kernel<<<dim3(8), dim3(256), 0, stream>>>(W_ih1, W_hh1, W_ih2, ws);
  dim3 grid(BATCH / 64), block(512);   // 8 role-waves, 2 blk/CU, 4 waves/SIMD
  sampler_kernel<<<grid, block, 0, stream>>>(mu, log_var, ws, b_ih1, b_hh1,
                                             W_hh2, b_ih2, b_hh2, out);
}

// Round 7
// 546.654 us; speedup vs baseline: 1.4429x; 1.4253x over previous
//
#include <hip/hip_runtime.h>
#include <stdint.h>
#include <math.h>

#define BATCH 32768
#define LDIM 128
#define HID 20

// workspace layout (dwords):
//   WS_WC    f32  [wv8][col127][i10]        = 10160   (acc prefix, exact f32)
//   WS_WHH16 u32  [wv8][kl5][tyl2][q10]     = 800     (f16-pair W_hh1)
//   WS_WI216 u32  [kr4][kl5][j8]            = 160     (f16 (lh,lc)-interleaved W_ih2)
#define WS_WC    0
#define WS_WHH16 10160
#define WS_WI216 10960
#define WS_TOTAL 11120

// =====================================================================
// eps: jax.random.normal(key(42), (128,32768), f32), partitionable
// threefry (counters (0,n), output o0^o1) — VERIFIED PASSING (r4/r5,
// absmax 0.0156 = 1 bf16 ulp). Do not touch.
// =====================================================================

__device__ __forceinline__ void threefry2x32(uint32_t x0, uint32_t x1,
                                             uint32_t& o0, uint32_t& o1) {
  const uint32_t k0 = 0u, k1 = 42u;
  const uint32_t k2 = k0 ^ k1 ^ 0x1BD11BDAu;
  uint32_t v0 = x0 + k0, v1 = x1 + k1;
#define TF_R(r) { v0 += v1; v1 = (v1 << (r)) | (v1 >> (32 - (r))); v1 ^= v0; }
  TF_R(13) TF_R(15) TF_R(26) TF_R(6)
  v0 += k1; v1 += k2 + 1u;
  TF_R(17) TF_R(29) TF_R(16) TF_R(24)
  v0 += k2; v1 += k0 + 2u;
  TF_R(13) TF_R(15) TF_R(26) TF_R(6)
  v0 += k0; v1 += k1 + 3u;
  TF_R(17) TF_R(29) TF_R(16) TF_R(24)
  v0 += k1; v1 += k2 + 4u;
  TF_R(13) TF_R(15) TF_R(26) TF_R(6)
  v0 += k2; v1 += k0 + 5u;
#undef TF_R
  o0 = v0; o1 = v1;
}

__device__ __forceinline__ float erfinv_xla_f32(float x) {
  float t = __fmul_rn(x, x);
  float w = -(float)log1p(-(double)t);   // correctly-rounded f32 log1p
  float p;
  if (w < 5.0f) {
    w = __fadd_rn(w, -2.5f);
    p = 2.81022636e-08f;
    p = __fadd_rn(__fmul_rn(p, w), 3.43273939e-07f);
    p = __fadd_rn(__fmul_rn(p, w), -3.5233877e-06f);
    p = __fadd_rn(__fmul_rn(p, w), -4.39150654e-06f);
    p = __fadd_rn(__fmul_rn(p, w), 0.00021858087f);
    p = __fadd_rn(__fmul_rn(p, w), -0.00125372503f);
    p = __fadd_rn(__fmul_rn(p, w), -0.00417768164f);
    p = __fadd_rn(__fmul_rn(p, w), 0.246640727f);
    p = __fadd_rn(__fmul_rn(p, w), 1.50140941f);
  } else {
    w = __fadd_rn(__fsqrt_rn(w), -3.0f);
    p = -0.000200214257f;
    p = __fadd_rn(__fmul_rn(p, w), 0.000100950558f);
    p = __fadd_rn(__fmul_rn(p, w), 0.00134934322f);
    p = __fadd_rn(__fmul_rn(p, w), -0.00367342844f);
    p = __fadd_rn(__fmul_rn(p, w), 0.00573950773f);
    p = __fadd_rn(__fmul_rn(p, w), -0.0076224613f);
    p = __fadd_rn(__fmul_rn(p, w), 0.00943887047f);
    p = __fadd_rn(__fmul_rn(p, w), 1.00167406f);
    p = __fadd_rn(__fmul_rn(p, w), 2.83297682f);
  }
  return __fmul_rn(p, x);
}

__device__ __forceinline__ float eps_val(int t, int b) {
  uint32_t n = (uint32_t)t * 32768u + (uint32_t)b;
  uint32_t o0, o1;
  threefry2x32(0u, n, o0, o1);
  uint32_t bits = o0 ^ o1;
  const float lo    = __uint_as_float(0xBF7FFFFFu);
  const float sqrt2 = __uint_as_float(0x3FB504F3u);
  float f = __fadd_rn(__uint_as_float((bits >> 9) | 0x3F800000u), -1.0f);
  float u = __fadd_rn(__fmul_rn(f, 2.0f), lo);
  u = fmaxf(u, lo);
  return __fmul_rn(sqrt2, erfinv_xla_f32(u));
}

__device__ __forceinline__ float fexp2(float x) { return __builtin_amdgcn_exp2f(x); }
__device__ __forceinline__ float frcp(float x)  { return __builtin_amdgcn_rcpf(x); }
__device__ __forceinline__ float fexp(float x)  { return fexp2(1.442695040888963f * x); }
__device__ __forceinline__ float sigm(float x)  { return frcp(1.0f + fexp2(-1.442695040888963f * x)); }
__device__ __forceinline__ float tanhx(float x) { return 1.0f - 2.0f * frcp(1.0f + fexp2(2.885390081777926f * x)); }

typedef _Float16 h2_t __attribute__((ext_vector_type(2)));

// RNE f16 pair pack (f32 -> 2xf16 in one dword)
__device__ __forceinline__ uint32_t packh(float x, float y) {
  h2_t p;
  p.x = (_Float16)x;
  p.y = (_Float16)y;
  return __builtin_bit_cast(uint32_t, p);
}

// full-rate 2-way f16 dot with f32 accumulate: d = a.lo*b.lo + a.hi*b.hi + c
// via the canonical DL intrinsic (v_dot2_f32_f16) — no inline asm (the r6
// container failure's only plausible kernel-side cause was the asm operand
// constraints; the builtin carries zero assembly-syntax risk).
__device__ __forceinline__ float dot2f16(uint32_t a, uint32_t b, float c) {
  return __builtin_amdgcn_fdot2(__builtin_bit_cast(h2_t, a),
                                __builtin_bit_cast(h2_t, b), c, false);
}

// repack: Wcol f32 (exact acc path) + W_hh1/W_ih2 as f16 pairs for dot2.
__global__ void repack_kernel(const float* __restrict__ W_ih1,
                              const float* __restrict__ W_hh1,
                              const float* __restrict__ W_ih2,
                              float* __restrict__ ws) {
  uint32_t* wsu = (uint32_t*)ws;
  const int stride = gridDim.x * blockDim.x;
  const int tid0 = blockIdx.x * blockDim.x + threadIdx.x;
  for (int idx = tid0; idx < 10160; idx += stride) {  // Wc f32 [wv][col][i10]
    int i = idx % 10, rc = idx / 10;
    int col = rc % 127, wv = rc / 127;
    int tp = wv >> 2, kr = wv & 3;
    int tyl = i / 5, kl = i % 5;
    int g = (2 * tp + tyl) * 20 + kr * 5 + kl;
    ws[WS_WC + idx] = W_ih1[g * 127 + col];
  }
  for (int idx = tid0; idx < 800; idx += stride) {    // Whh16 [wv][kl][tyl][q10]
    int q = idx % 10, r = idx / 10;     // r = ((wv*5+kl)*2+tyl)
    int tyl = r & 1, rkl = r >> 1;
    int kl = rkl % 5, wv = rkl / 5;
    int tp = wv >> 2, kr = wv & 3;
    int g = (2 * tp + tyl) * 20 + kr * 5 + kl;
    wsu[WS_WHH16 + idx] = packh(W_hh1[g * 20 + 2 * q], W_hh1[g * 20 + 2 * q + 1]);
  }
  for (int idx = tid0; idx < 160; idx += stride) {    // Wi216 [kr][kl][j8]
    int j = idx % 8, r = idx / 8;       // r = kr*5+kl = k
    int kl = r % 5, kr = r / 5;
    int k = kr * 5 + kl;
    wsu[WS_WI216 + idx] = packh(W_ih2[j * 40 + k], W_ih2[j * 40 + 20 + k]);
  }
}

// V7b = r6 skeleton + v_dot2_f32_f16 (via builtin) for the two GEMV hot
// loops. r5 post-mortem: VALU-execution-bound (op count 10.8K cy/step ==
// measured busy-cycles). dot2 halves the dominant h@Whh dot (20 fma -> 10
// dot2/gate) and g2p (16 fma -> 8 dot2/k). acc prefix, cell, LSTM2, eps
// stay exact f32.
__global__ __launch_bounds__(512, 4) void sampler_kernel(
    const float* __restrict__ mu, const float* __restrict__ log_var,
    const float* __restrict__ ws,
    const float* __restrict__ b_ih1, const float* __restrict__ b_hh1,
    const float* __restrict__ W_hh2,
    const float* __restrict__ b_ih2, const float* __restrict__ b_hh2,
    float* __restrict__ out) {
  __shared__ float hbuf[HID][64];        // h1(t): written B, read C
  __shared__ float gko[4][5][2][64];     // gk,ok: written A, read B
  __shared__ float gbuf[8][4][64];       // g2 partials: written B, read C
  __shared__ float h2buf[2][2][64];      // h2 (dbuf: crosses steps)
  __shared__ float epsbuf[2][4][64];     // eps ring (8-step period)

  const int tid  = threadIdx.x;
  const int lane = tid & 63;
  const int wv   = __builtin_amdgcn_readfirstlane(tid >> 6);  // 0..7 uniform
  const int tp   = wv >> 2;             // 0: types i,f   1: types g,o
  const int kr   = wv & 3;              // k = kr*5 + kl
  const int elem = blockIdx.x * 64 + lane;
  const float* mrow = mu + (size_t)elem * LDIM;

  // wave-local weight bases (uniform → scalar loads)
  const float*    Wcol = ws + WS_WC + wv * (127 * 10);   // + col*10 (f32)
  const uint32_t* wsu  = (const uint32_t*)ws;
  const uint32_t* Whh  = wsu + WS_WHH16 + wv * 100;      // + kl*20 (f16 pairs)
  const uint32_t* Wi2  = wsu + WS_WI216 + kr * 40;       // + kl*8  (f16 pairs)

  // first_input (replicated on all 8 waves; bit-identical)
  float eps0 = eps_val(0, elem);
  float m0 = mrow[0];
  float fi = fmaf(eps0, fexp(0.5f * log_var[(size_t)elem * LDIM]), m0);

  // acc[i], i = tyl*5+kl — this wave's 10 gate accumulators, bias folded.
  float acc[10];
#pragma unroll
  for (int i = 0; i < 10; ++i) {
    const int tyl = i / 5, kl = i % 5;
    const int g = (2 * tp + tyl) * 20 + kr * 5 + kl;   // uniform
    acc[i] = fmaf(fi, Wcol[i], b_ih1[g] + b_hh1[g]);   // Wcol col 0
  }

  uint32_t h16[10];                      // h1 as f16 pairs (j,j+1)
#pragma unroll
  for (int q = 0; q < 10; ++q) h16[q] = 0u;
  float cst[5];                          // live on tp==0 waves
#pragma unroll
  for (int k = 0; k < 5; ++k) cst[k] = 0.0f;
  float h2a = 0.0f, h2b = 0.0f, c2a = 0.0f, c2b = 0.0f;  // live on wave 4

  float* out_mu = out;
  float* out_lv = out + (size_t)BATCH * LDIM;
  float* out_sp = out + 2 * (size_t)BATCH * LDIM;
  const size_t rowoff = (size_t)elem * LDIM;
  if (wv == 5)      out_sp[rowoff] = fi;
  else if (wv == 6) { out_mu[rowoff] = 0.0f; out_lv[rowoff] = 1.0f; }

  float xm_pref = m0;

  for (int t = 1; t < LDIM; ++t) {
    const int buf = t & 1;
    float xm = xm_pref;
    xm_pref = mrow[t];

    // ======== phase A (all waves) ========
    if (tp == 1 && ((t - 1) & 3) == 0)
      epsbuf[((t - 1) >> 2) & 1][kr][lane] = eps_val((t - 1) + kr, elem);

    // maintain acc = bias + (input cols) @ W_ih1^T (prefix trick, exact f32)
    if (t >= 2) {
      if (t == 2) {
        float d0 = m0 - fi;   // col 0 switches first_input -> mu[:,0]
#pragma unroll
        for (int i = 0; i < 10; ++i) acc[i] = fmaf(d0, Wcol[i], acc[i]);
      }
      const float* wc = Wcol + (t - 1) * 10;           // contiguous 10 dwords
#pragma unroll
      for (int i = 0; i < 10; ++i) acc[i] = fmaf(xm, wc[i], acc[i]);
    }

    // this wave's 10 dots (2 types × 5 k) via full-rate f16 dot2
    float a0[5], a1[5];     // tp0: ik,fk    tp1: gk,ok
#pragma unroll
    for (int kl = 0; kl < 5; ++kl) {
      float s0 = acc[kl], s1 = acc[5 + kl];
      const uint32_t* w0 = Whh + kl * 20;              // 20 u32 = 2 gates
#pragma unroll
      for (int q = 0; q < 10; ++q) {
        s0 = dot2f16(h16[q], w0[q], s0);
        s1 = dot2f16(h16[q], w0[10 + q], s1);
      }
      if (tp == 0) { a0[kl] = sigm(s0);  a1[kl] = sigm(s1); }   // ik, fk
      else         { a0[kl] = tanhx(s0); a1[kl] = sigm(s1); }   // gk, ok
    }
    if (tp == 1) {
#pragma unroll
      for (int kl = 0; kl < 5; ++kl) {
        gko[kr][kl][0][lane] = a0[kl];                 // gk
        gko[kr][kl][1][lane] = a1[kl];                 // ok
      }
    }

    __syncthreads();   // barrier 1: gko ready

    // ======== phase B (tp0 waves): cell + fused LSTM2 partials ========
    if (tp == 0) {
      float g2p[8];
#pragma unroll
      for (int j = 0; j < 8; ++j) g2p[j] = 0.0f;
#pragma unroll
      for (int kl = 0; kl < 5; ++kl) {
        float gk = gko[kr][kl][0][lane];
        float ok = gko[kr][kl][1][lane];
        float cn = fmaf(a1[kl], cst[kl], a0[kl] * gk); // fk*c + ik*gk
        cst[kl] = cn;
        float hk = ok * tanhx(cn);
        hbuf[kr * 5 + kl][lane] = hk;
        float lh = (hk >= 0.0f) ? hk : 0.01f * hk;
        float lc = (cn >= 0.0f) ? cn : 0.01f * cn;
        uint32_t lhlc = packh(lh, lc);
        const uint32_t* u = Wi2 + kl * 8;              // 8 u32 (f16 pairs)
#pragma unroll
        for (int j = 0; j < 8; ++j) g2p[j] = dot2f16(lhlc, u[j], g2p[j]);
      }
#pragma unroll
      for (int j = 0; j < 8; ++j) gbuf[j][kr][lane] = g2p[j];
    }

    __syncthreads();   // barrier 2: hbuf + gbuf ready

    // ======== phase C ========
#pragma unroll
    for (int q = 0; q < 10; ++q)
      h16[q] = packh(hbuf[2 * q][lane], hbuf[2 * q + 1][lane]);

    if (wv == 4) {
      // wave (1,0): LSTM2 reduce + cell (sole owner of h2/c2 state, f32)
      float g2[8];
#pragma unroll
      for (int j = 0; j < 8; ++j) {
        float p0 = gbuf[j][0][lane];
        float p1 = gbuf[j][1][lane];
        float p2 = gbuf[j][2][lane];
        float p3 = gbuf[j][3][lane];
        float v = (p0 + p1) + (p2 + p3);
        g2[j] = fmaf(h2a, W_hh2[2 * j],
                     fmaf(h2b, W_hh2[2 * j + 1], b_ih2[j] + b_hh2[j])) + v;
      }
      float i20 = sigm(g2[0]), i21 = sigm(g2[1]);
      float f20 = sigm(g2[2]), f21 = sigm(g2[3]);
      float t20 = tanhx(g2[4]), t21 = tanhx(g2[5]);
      float o20 = sigm(g2[6]), o21 = sigm(g2[7]);
      c2a = fmaf(f20, c2a, i20 * t20);
      c2b = fmaf(f21, c2b, i21 * t21);
      h2a = o20 * tanhx(c2a);
      h2b = o21 * tanhx(c2b);
      h2buf[buf][0][lane] = h2a;
      h2buf[buf][1][lane] = h2b;
    } else if (wv == 5) {
      if (t >= 2) {                                    // sample for col t-1
        const int e = t - 1;
        float h2a_p = h2buf[buf ^ 1][0][lane];
        float h2b_p = h2buf[buf ^ 1][1][lane];
        float eps_t = epsbuf[(e >> 2) & 1][e & 3][lane];
        out_sp[rowoff + e] = fmaf(eps_t, fexp(0.5f * h2b_p), h2a_p);
      }
    } else if (wv == 6) {
      if (t >= 2) {                                    // mu/lv for col t-1
        out_mu[rowoff + (t - 1)] = h2buf[buf ^ 1][0][lane];
        out_lv[rowoff + (t - 1)] = h2buf[buf ^ 1][1][lane];
      }
    }
  }

  // ---- drain col 127 (t=127 wrote h2buf[1]) ----
  __syncthreads();
  if (wv == 5) {
    float eps_t = epsbuf[1][3][lane];                  // eps(127): grp 31
    out_sp[rowoff + 127] = fmaf(eps_t, fexp(0.5f * h2buf[1][1][lane]),
                                h2buf[1][0][lane]);
  } else if (wv == 6) {
    out_mu[rowoff + 127] = h2buf[1][0][lane];
    out_lv[rowoff + 127] = h2buf[1][1][lane];
  }
}

extern "C" void kernel_launch(void* const* d_in, const int* in_sizes, int n_in,
                              void* d_out, int out_size, void* d_ws, size_t ws_size,
                              hipStream_t stream) {
  (void)in_sizes; (void)n_in; (void)ws_size; (void)out_size;
  const float* mu      = (const float*)d_in[0];
  const float* log_var = (const float*)d_in[1];
  const float* W_ih1   = (const float*)d_in[2];
  const float* W_hh1   = (const float*)d_in[3];
  const float* b_ih1   = (const float*)d_in[4];
  const float* b_hh1   = (const float*)d_in[5];
  const float* W_ih2   = (const float*)d_in[6];
  const float* W_hh2   = (const float*)d_in[7];
  const float* b_ih2   = (const float*)d_in[8];
  const float* b_hh2   = (const float*)d_in[9];
  float* out = (float*)d_out;
  float* ws  = (float*)d_ws;   // needs 11120 dwords = 44.5 KB

  repack_kernel<<<dim3(8), dim3(256), 0, stream>>>(W_ih1, W_hh1, W_ih2, ws);
  dim3 grid(BATCH / 64), block(512);   // 8 role-waves, 2 blk/CU
  sampler_kernel<<<grid, block, 0, stream>>>(mu, log_var, ws, b_ih1, b_hh1,
                                             W_hh2, b_ih2, b_hh2, out);
}

// Round 8
// 335.464 us; speedup vs baseline: 2.3513x; 1.6295x over previous
//
#include <hip/hip_runtime.h>
#include <stdint.h>
#include <math.h>

#define BATCH 32768
#define LDIM 128
#define HID 20

// ws layout (dword offsets):
//   WS_AW  u32 [m5][lane64][q4]   = 1280   A-fragments of Whh1 (f16 pairs)
//   WS_AU  u32 [ks2][lane64][q4]  = 512    A-fragments of W_ih2 (f16 pairs)
//   WS_WCD f32 [col127][grow80]   = 10160  W_ih1 cols, grow = 4*unit+type (f32 exact)
#define WS_AW  0
#define WS_AU  1280
#define WS_WCD 1792
#define WS_TOTAL 11952

// =====================================================================
// eps: jax.random.normal(key(42), (128,32768), f32), partitionable
// threefry (counters (0,n), output o0^o1) — VERIFIED PASSING. Do not touch.
// =====================================================================

__device__ __forceinline__ void threefry2x32(uint32_t x0, uint32_t x1,
                                             uint32_t& o0, uint32_t& o1) {
  const uint32_t k0 = 0u, k1 = 42u;
  const uint32_t k2 = k0 ^ k1 ^ 0x1BD11BDAu;
  uint32_t v0 = x0 + k0, v1 = x1 + k1;
#define TF_R(r) { v0 += v1; v1 = (v1 << (r)) | (v1 >> (32 - (r))); v1 ^= v0; }
  TF_R(13) TF_R(15) TF_R(26) TF_R(6)
  v0 += k1; v1 += k2 + 1u;
  TF_R(17) TF_R(29) TF_R(16) TF_R(24)
  v0 += k2; v1 += k0 + 2u;
  TF_R(13) TF_R(15) TF_R(26) TF_R(6)
  v0 += k0; v1 += k1 + 3u;
  TF_R(17) TF_R(29) TF_R(16) TF_R(24)
  v0 += k1; v1 += k2 + 4u;
  TF_R(13) TF_R(15) TF_R(26) TF_R(6)
  v0 += k2; v1 += k0 + 5u;
#undef TF_R
  o0 = v0; o1 = v1;
}

__device__ __forceinline__ float erfinv_xla_f32(float x) {
  float t = __fmul_rn(x, x);
  float w = -(float)log1p(-(double)t);   // correctly-rounded f32 log1p
  float p;
  if (w < 5.0f) {
    w = __fadd_rn(w, -2.5f);
    p = 2.81022636e-08f;
    p = __fadd_rn(__fmul_rn(p, w), 3.43273939e-07f);
    p = __fadd_rn(__fmul_rn(p, w), -3.5233877e-06f);
    p = __fadd_rn(__fmul_rn(p, w), -4.39150654e-06f);
    p = __fadd_rn(__fmul_rn(p, w), 0.00021858087f);
    p = __fadd_rn(__fmul_rn(p, w), -0.00125372503f);
    p = __fadd_rn(__fmul_rn(p, w), -0.00417768164f);
    p = __fadd_rn(__fmul_rn(p, w), 0.246640727f);
    p = __fadd_rn(__fmul_rn(p, w), 1.50140941f);
  } else {
    w = __fadd_rn(__fsqrt_rn(w), -3.0f);
    p = -0.000200214257f;
    p = __fadd_rn(__fmul_rn(p, w), 0.000100950558f);
    p = __fadd_rn(__fmul_rn(p, w), 0.00134934322f);
    p = __fadd_rn(__fmul_rn(p, w), -0.00367342844f);
    p = __fadd_rn(__fmul_rn(p, w), 0.00573950773f);
    p = __fadd_rn(__fmul_rn(p, w), -0.0076224613f);
    p = __fadd_rn(__fmul_rn(p, w), 0.00943887047f);
    p = __fadd_rn(__fmul_rn(p, w), 1.00167406f);
    p = __fadd_rn(__fmul_rn(p, w), 2.83297682f);
  }
  return __fmul_rn(p, x);
}

__device__ __forceinline__ float eps_val(int t, int b) {
  uint32_t n = (uint32_t)t * 32768u + (uint32_t)b;
  uint32_t o0, o1;
  threefry2x32(0u, n, o0, o1);
  uint32_t bits = o0 ^ o1;
  const float lo    = __uint_as_float(0xBF7FFFFFu);
  const float sqrt2 = __uint_as_float(0x3FB504F3u);
  float f = __fadd_rn(__uint_as_float((bits >> 9) | 0x3F800000u), -1.0f);
  float u = __fadd_rn(__fmul_rn(f, 2.0f), lo);
  u = fmaxf(u, lo);
  return __fmul_rn(sqrt2, erfinv_xla_f32(u));
}

__device__ __forceinline__ float fexp2(float x) { return __builtin_amdgcn_exp2f(x); }
__device__ __forceinline__ float frcp(float x)  { return __builtin_amdgcn_rcpf(x); }
__device__ __forceinline__ float fexp(float x)  { return fexp2(1.442695040888963f * x); }
__device__ __forceinline__ float sigm(float x)  { return frcp(1.0f + fexp2(-1.442695040888963f * x)); }
__device__ __forceinline__ float tanhx(float x) { return 1.0f - 2.0f * frcp(1.0f + fexp2(2.885390081777926f * x)); }

typedef _Float16 f16x8 __attribute__((ext_vector_type(8)));
typedef _Float16 f16x2 __attribute__((ext_vector_type(2)));
typedef float    f32x4 __attribute__((ext_vector_type(4)));

__device__ __forceinline__ uint32_t packh(float x, float y) {
  f16x2 p;
  p.x = (_Float16)x;
  p.y = (_Float16)y;
  return __builtin_bit_cast(uint32_t, p);
}

// =====================================================================
// repack: build MFMA A-fragments (f16) + grow-ordered W_ih1 cols (f32).
// Fragment convention (canonical CDNA, m89-verified C/D):
//   A (M16 x K32): lane l holds row = l&15, k = (l>>4)*8 + half(0..7)
//   B (K32 x N16): lane l holds col = l&15, k = (l>>4)*8 + half
//   D: col = l&15, row = (l>>4)*4 + reg
// Gate-row order grow = 4*unit + type so D lane (sub=l>>4) holds all 4
// gate types of unit (4m+sub) in regs 0..3.
// Any k-permutation error cancels: A and B both built with same mapping.
// =====================================================================
__global__ void repack_kernel(const float* __restrict__ W_ih1,
                              const float* __restrict__ W_hh1,
                              const float* __restrict__ W_ih2,
                              float* __restrict__ ws) {
  uint32_t* wsu = (uint32_t*)ws;
  const int stride = gridDim.x * blockDim.x;
  const int tid0 = blockIdx.x * blockDim.x + threadIdx.x;
  for (int idx = tid0; idx < 1280; idx += stride) {   // A_whh [m][l][q]
    int q = idx & 3, l = (idx >> 2) & 63, m = idx >> 8;
    int rA = l & 15, koct = l >> 4;
    int ty = rA & 3, u = 4 * m + (rA >> 2);
    int k0 = koct * 8 + 2 * q, k1 = k0 + 1;
    float w0 = (k0 < 20) ? W_hh1[(ty * 20 + u) * 20 + k0] : 0.0f;
    float w1 = (k1 < 20) ? W_hh1[(ty * 20 + u) * 20 + k1] : 0.0f;
    wsu[WS_AW + idx] = packh(w0, w1);
  }
  for (int idx = tid0; idx < 512; idx += stride) {    // A_u [ks][l][q]
    int q = idx & 3, l = (idx >> 2) & 63, ks = idx >> 8;
    int j = l & 15, koct = l >> 4;
    int kk0 = ks * 32 + koct * 8 + 2 * q, kk1 = kk0 + 1;
    float w0 = (j < 8 && kk0 < 40)
                   ? W_ih2[j * 40 + (kk0 & 1) * 20 + (kk0 >> 1)] : 0.0f;
    float w1 = (j < 8 && kk1 < 40)
                   ? W_ih2[j * 40 + (kk1 & 1) * 20 + (kk1 >> 1)] : 0.0f;
    wsu[WS_AU + idx] = packh(w0, w1);
  }
  for (int idx = tid0; idx < 10160; idx += stride) {  // Wc [col][grow]
    int grow = idx % 80, col = idx / 80;
    int u = grow >> 2, ty = grow & 3;
    ws[WS_WCD + idx] = W_ih1[(ty * 20 + u) * 127 + col];
  }
}

// V8: wave-independent MFMA sampler. Each wave owns 16 elems (elem = l&15,
// sub = l>>4); NO barriers in the t-loop (r7 post-mortem: barrier+phase
// serialization left wall 4.5x above issue-bound). Per step:
//   5 MFMA (gates, C = exact-f32 acc) + 2 MFMA (LSTM2 partials) +
//   lane-local activations/cell + tiny wave-synchronous LDS h/lhlc exchange.
// acc prefix, cell, LSTM2, eps stay exact f32 (same orderings as r7).
__global__ __launch_bounds__(256, 1) void sampler_kernel(
    const float* __restrict__ mu, const float* __restrict__ log_var,
    const float* __restrict__ ws,
    const float* __restrict__ b_ih1, const float* __restrict__ b_hh1,
    const float* __restrict__ W_hh2,
    const float* __restrict__ b_ih2, const float* __restrict__ b_hh2,
    float* __restrict__ out) {
  __shared__ float WcL[10160];                       // [col][grow80] f32
  __shared__ __align__(16) _Float16 hsh[4][640];     // per wave: [elem16][40h]
  __shared__ __align__(16) _Float16 lsh[4][1152];    // per wave: [elem16][72h]

  const int tid  = threadIdx.x;
  const int lane = tid & 63;
  const int wvl  = __builtin_amdgcn_readfirstlane(tid >> 6);
  const int sub  = lane >> 4;                        // 0..3
  const int el   = lane & 15;
  const int elem = blockIdx.x * 64 + wvl * 16 + el;

  // stage Wc (f32, exact) + zero the exchange pads
  for (int i = tid; i < 10160; i += 256) WcL[i] = ws[WS_WCD + i];
  {
    uint32_t* hz = (uint32_t*)&hsh[0][0];
    for (int i = tid; i < 1280; i += 256) hz[i] = 0u;
    uint32_t* lz = (uint32_t*)&lsh[0][0];
    for (int i = tid; i < 2304; i += 256) lz[i] = 0u;
  }

  // A-fragments (constant across loop): coalesced 16B/lane global loads
  const uint32_t* wsu = (const uint32_t*)ws;
  f16x8 aw[5], au[2];
#pragma unroll
  for (int m = 0; m < 5; ++m)
    aw[m] = *(const f16x8*)(wsu + WS_AW + (m * 64 + lane) * 4);
#pragma unroll
  for (int ks = 0; ks < 2; ++ks)
    au[ks] = *(const f16x8*)(wsu + WS_AU + (ks * 64 + lane) * 4);

  __syncthreads();   // the only barrier: WcL + zero-init ready

  _Float16* hrow = &hsh[wvl][el * 40];               // 80B rows (16B-aligned)
  _Float16* lrow = &lsh[wvl][el * 72];               // 144B rows (16B-aligned)

  const float* mrow = mu + (size_t)elem * LDIM;

  // tiny LSTM2 weights: uniform scalar loads
  float w2[16], b2s[8];
#pragma unroll
  for (int i = 0; i < 16; ++i) w2[i] = W_hh2[i];
#pragma unroll
  for (int i = 0; i < 8; ++i)  b2s[i] = b_ih2[i] + b_hh2[i];

  // first_input (replicated on the 4 sub-lanes of each elem; bit-identical)
  float eps0 = eps_val(0, elem);
  float m0 = mrow[0];
  float fi = fmaf(eps0, fexp(0.5f * log_var[(size_t)elem * LDIM]), m0);

  // acc = C-operand of the gates MFMA: exact-f32 input-projection prefix,
  // bias folded (same per-gate fmaf sequence as r7 → bit-exact acc).
  f32x4 acc[5];
#pragma unroll
  for (int m = 0; m < 5; ++m) {
    f32x4 w0 = *(const f32x4*)&WcL[16 * m + 4 * sub];
#pragma unroll
    for (int r = 0; r < 4; ++r) {
      const int grow = 16 * m + 4 * sub + r;
      const int g = (grow & 3) * 20 + (grow >> 2);
      acc[m][r] = fmaf(fi, w0[r], b_ih1[g] + b_hh1[g]);
    }
  }

  float cst[5];
#pragma unroll
  for (int m = 0; m < 5; ++m) cst[m] = 0.0f;
  float h2a = 0.0f, h2b = 0.0f, c2a = 0.0f, c2b = 0.0f;

  float* out_mu = out;
  float* out_lv = out + (size_t)BATCH * LDIM;
  float* out_sp = out + 2 * (size_t)BATCH * LDIM;
  const size_t rowoff = (size_t)elem * LDIM;
  if (sub == 0)      { out_mu[rowoff] = 0.0f; out_lv[rowoff] = 1.0f; }
  else if (sub == 1) { out_sp[rowoff] = fi; }

  const f32x4 z4 = {0.0f, 0.0f, 0.0f, 0.0f};
  float xm_pref = m0;
  float eps4 = 0.0f;

  for (int t = 1; t < LDIM; ++t) {
    float xm = xm_pref;
    xm_pref = mrow[t];

    // eps: every 4 steps sub s computes eps(t+s); consumer shuffles (in-wave)
    if (((t - 1) & 3) == 0) eps4 = eps_val(t + sub, elem);

    // ---- acc prefix (exact f32, r7-identical ordering) ----
    if (t >= 2) {
      if (t == 2) {
        float d0 = m0 - fi;   // col 0 switches first_input -> mu[:,0]
#pragma unroll
        for (int m = 0; m < 5; ++m) {
          f32x4 w0 = *(const f32x4*)&WcL[16 * m + 4 * sub];
#pragma unroll
          for (int r = 0; r < 4; ++r) acc[m][r] = fmaf(d0, w0[r], acc[m][r]);
        }
      }
#pragma unroll
      for (int m = 0; m < 5; ++m) {
        f32x4 wc = *(const f32x4*)&WcL[(t - 1) * 80 + 16 * m + 4 * sub];
#pragma unroll
        for (int r = 0; r < 4; ++r) acc[m][r] = fmaf(xm, wc[r], acc[m][r]);
      }
    }

    // ---- gates = Whh @ h^T + acc : 5 MFMA ----
    f16x8 bh = *(const f16x8*)&hrow[sub * 8];        // B-frag: h(t-1), k-octet
    f32x4 d[5];
#pragma unroll
    for (int m = 0; m < 5; ++m)
      d[m] = __builtin_amdgcn_mfma_f32_16x16x32_f16(aw[m], bh, acc[m], 0, 0, 0);

    // ---- activations + cell (lane owns unit 4m+sub, all 4 types) ----
#pragma unroll
    for (int m = 0; m < 5; ++m) {
      float ik = sigm(d[m][0]), fk = sigm(d[m][1]);
      float gk = tanhx(d[m][2]), ok = sigm(d[m][3]);
      float cn = fmaf(fk, cst[m], ik * gk);
      cst[m] = cn;
      float hk = ok * tanhx(cn);
      hrow[4 * m + sub] = (_Float16)hk;              // h for next step's B
      float lh = (hk >= 0.0f) ? hk : 0.01f * hk;
      float lc = (cn >= 0.0f) ? cn : 0.01f * cn;
      f16x2 p; p.x = (_Float16)lh; p.y = (_Float16)lc;
      ((f16x2*)lrow)[4 * m + sub] = p;               // kk = 2*unit + {lh,lc}
    }

    // ---- LSTM2 partials: U[8x40] @ lhlc^T : 2 chained MFMA ----
    // (wave-synchronous LDS: in-order DS pipe, writes above precede reads)
    f16x8 bl0 = *(const f16x8*)&lrow[sub * 8];
    f16x8 bl1 = *(const f16x8*)&lrow[32 + sub * 8];
    f32x4 d2 = __builtin_amdgcn_mfma_f32_16x16x32_f16(au[0], bl0, z4, 0, 0, 0);
    d2 = __builtin_amdgcn_mfma_f32_16x16x32_f16(au[1], bl1, d2, 0, 0, 0);
    // D2 rows: sub0 = j0..3, sub1 = j4..7; exchange via xor-16 shuffle
    float e0 = __shfl_xor(d2[0], 16, 64);
    float e1 = __shfl_xor(d2[1], 16, 64);
    float e2 = __shfl_xor(d2[2], 16, 64);
    float e3 = __shfl_xor(d2[3], 16, 64);
    const bool s1 = (sub == 1);
    float v0 = s1 ? e0 : d2[0], v1 = s1 ? e1 : d2[1];
    float v2 = s1 ? e2 : d2[2], v3 = s1 ? e3 : d2[3];
    float v4 = s1 ? d2[0] : e0, v5 = s1 ? d2[1] : e1;
    float v6 = s1 ? d2[2] : e2, v7 = s1 ? d2[3] : e3;

    float g0 = fmaf(h2a, w2[0],  fmaf(h2b, w2[1],  b2s[0])) + v0;
    float g1 = fmaf(h2a, w2[2],  fmaf(h2b, w2[3],  b2s[1])) + v1;
    float g2 = fmaf(h2a, w2[4],  fmaf(h2b, w2[5],  b2s[2])) + v2;
    float g3 = fmaf(h2a, w2[6],  fmaf(h2b, w2[7],  b2s[3])) + v3;
    float g4 = fmaf(h2a, w2[8],  fmaf(h2b, w2[9],  b2s[4])) + v4;
    float g5 = fmaf(h2a, w2[10], fmaf(h2b, w2[11], b2s[5])) + v5;
    float g6 = fmaf(h2a, w2[12], fmaf(h2b, w2[13], b2s[6])) + v6;
    float g7 = fmaf(h2a, w2[14], fmaf(h2b, w2[15], b2s[7])) + v7;

    float i20 = sigm(g0), i21 = sigm(g1);
    float f20 = sigm(g2), f21 = sigm(g3);
    float t20 = tanhx(g4), t21 = tanhx(g5);
    float o20 = sigm(g6), o21 = sigm(g7);
    c2a = fmaf(f20, c2a, i20 * t20);
    c2b = fmaf(f21, c2b, i21 * t21);
    h2a = o20 * tanhx(c2a);
    h2b = o21 * tanhx(c2b);

    // ---- sample + stores (sub-split; subs 2/3 idle here) ----
    float eps_t = __shfl(eps4, ((t - 1) & 3) * 16 + el, 64);
    if (sub == 0) {
      out_mu[rowoff + t] = h2a;
      out_lv[rowoff + t] = h2b;
    } else if (sub == 1) {
      out_sp[rowoff + t] = fmaf(eps_t, fexp(0.5f * h2b), h2a);
    }
  }
}

extern "C" void kernel_launch(void* const* d_in, const int* in_sizes, int n_in,
                              void* d_out, int out_size, void* d_ws, size_t ws_size,
                              hipStream_t stream) {
  (void)in_sizes; (void)n_in; (void)ws_size; (void)out_size;
  const float* mu      = (const float*)d_in[0];
  const float* log_var = (const float*)d_in[1];
  const float* W_ih1   = (const float*)d_in[2];
  const float* W_hh1   = (const float*)d_in[3];
  const float* b_ih1   = (const float*)d_in[4];
  const float* b_hh1   = (const float*)d_in[5];
  const float* W_ih2   = (const float*)d_in[6];
  const float* W_hh2   = (const float*)d_in[7];
  const float* b_ih2   = (const float*)d_in[8];
  const float* b_hh2   = (const float*)d_in[9];
  float* out = (float*)d_out;
  float* ws  = (float*)d_ws;   // needs 11952 dwords = 47.8 KB

  repack_kernel<<<dim3(8), dim3(256), 0, stream>>>(W_ih1, W_hh1, W_ih2, ws);
  dim3 grid(BATCH / 64), block(256);   // 4 waves/block, 16 elems/wave
  sampler_kernel<<<grid, block, 0, stream>>>(mu, log_var, ws, b_ih1, b_hh1,
                                             W_hh2, b_ih2, b_hh2, out);
}